// Round 7
// baseline (1840.776 us; speedup 1.0000x reference)
//
#include <hip/hip_runtime.h>

#define Tq     2048
#define INq    4
#define UNITSq 256
#define BBq    128
#define NCq    10
#define HBS    288   // hb row stride elems (576B; 576 mod 128B = 64 -> rows alternate 16-bank halves)
#define BBS    160   // bbuf row stride elems (320B; same parity trick)

typedef __bf16 bf16x8 __attribute__((ext_vector_type(8)));
typedef float  f32x4  __attribute__((ext_vector_type(4)));
typedef float  f32x2  __attribute__((ext_vector_type(2)));

__device__ __forceinline__ float rcpf(float x) { return __builtin_amdgcn_rcpf(x); }
__device__ __forceinline__ float tanh_f(float x) {
    float e = __expf(x + x);
    return 1.0f - 2.0f * rcpf(e + 1.0f);
}
__device__ __forceinline__ float lecun_f(float x) {
    float e = __expf(1.332f * x);
    return 1.7159f - 3.4318f * rcpf(e + 1.0f);
}
__device__ __forceinline__ float sigm_f(float x) {
    return rcpf(1.0f + __expf(-x));
}
__device__ __forceinline__ float sel4(f32x4 v, int i) {
    float lo = (i & 1) ? v[1] : v[0];
    float hi = (i & 1) ? v[3] : v[2];
    return (i & 2) ? hi : lo;
}

// LDS-only barrier: drain ds ops, block barrier, fence scheduler both sides
// (rule 18: sched_barrier(0) so MFMA/VALU aren't hoisted across).
__device__ __forceinline__ void bar_lds() {
    __builtin_amdgcn_sched_barrier(0);
    asm volatile("s_waitcnt lgkmcnt(0)" ::: "memory");
    __builtin_amdgcn_s_barrier();
    __builtin_amdgcn_sched_barrier(0);
}

// 256 blocks x 512 threads. Block owns batch rows [4b,4b+4).
// Row replication j&3: A-tile row j = real row (j&3); C/D reg i = real row i
// in every lane -> redistribution is a register select (sel4); lane's row = l4.
// Wave w: P0 cols [16w,16w+16); P1 units u = 32w + 2*lc + {0,1}.
// x (IN=4) handled on VALU: 4 fp32 FMAs per lane, off the MFMA critical path.
__global__ __launch_bounds__(512, 2) void cfc_kernel(
    const float* __restrict__ x,
    const float* __restrict__ W_bb, const float* __restrict__ b_bb,
    const float* __restrict__ W_ff1, const float* __restrict__ b_ff1,
    const float* __restrict__ W_ff2, const float* __restrict__ b_ff2,
    const float* __restrict__ W_ta, const float* __restrict__ b_ta,
    const float* __restrict__ W_tb, const float* __restrict__ b_tb,
    const float* __restrict__ W_fc, const float* __restrict__ b_fc,
    float* __restrict__ out)
{
    const int tid = threadIdx.x;
    const int w   = tid >> 6;
    const int l   = tid & 63;
    const int l4  = l >> 4;
    const int lc  = l & 15;
    const int bbase = blockIdx.x * 4;

    __shared__ __bf16 hb[4 * HBS];                   // cols 0..255 = h
    __shared__ __bf16 bbuf[4 * BBS];                 // cols 0..127 = bb
    __shared__ __align__(16) float xstage[2][512];   // 32 steps x 4 rows x 4
    __shared__ float  hsum_lds[4][256];

    // ---------------- weight preload (register-resident B-fragments) ---------
    bf16x8 WH[3][2][4];                  // [ff1, ff2, ta+tb][unit tile][ktile]
    #pragma unroll
    for (int tl = 0; tl < 2; ++tl) {
        const int u = w * 32 + 2 * lc + tl;
        #pragma unroll
        for (int kt = 0; kt < 4; ++kt) {
            bf16x8 f1, f2, ts;
            #pragma unroll
            for (int j = 0; j < 8; ++j) {
                const int k = kt * 32 + l4 * 8 + j;
                f1[j] = (__bf16)W_ff1[k * UNITSq + u];
                f2[j] = (__bf16)W_ff2[k * UNITSq + u];
                ts[j] = (__bf16)(W_ta[k * UNITSq + u] + W_tb[k * UNITSq + u]);
            }
            WH[0][tl][kt] = f1; WH[1][tl][kt] = f2; WH[2][tl][kt] = ts;
        }
    }
    const int cb = w * 16 + lc;
    bf16x8 WB[8];                        // h-part only (K = 256 exact)
    #pragma unroll
    for (int kt = 0; kt < 8; ++kt) {
        bf16x8 f;
        #pragma unroll
        for (int j = 0; j < 8; ++j) {
            const int k = kt * 32 + l4 * 8 + j;
            f[j] = (__bf16)W_bb[(4 + k) * BBq + cb];
        }
        WB[kt] = f;
    }
    // x-part of W_bb as fp32 (VALU path)
    const float Wx0 = W_bb[0 * BBq + cb];
    const float Wx1 = W_bb[1 * BBq + cb];
    const float Wx2 = W_bb[2 * BBq + cb];
    const float Wx3 = W_bb[3 * BBq + cb];

    const float bias_bb_r = b_bb[cb];
    const int ru0 = w * 32 + 2 * lc;
    const float bf1a = b_ff1[ru0], bf1b = b_ff1[ru0 + 1];
    const float bf2a = b_ff2[ru0], bf2b = b_ff2[ru0 + 1];
    const float bta_ = b_ta[ru0] + b_tb[ru0];
    const float btb_ = b_ta[ru0 + 1] + b_tb[ru0 + 1];

    // ---------------- init ---------------------------------------------------
    for (int i = tid; i < 4 * HBS; i += 512) hb[i] = (__bf16)0.0f;
    {
        const int r = tid >> 7, off = tid & 127;
        xstage[0][r * 128 + off] = x[((size_t)(bbase + r) * Tq + (off >> 2)) * INq + (off & 3)];
    }
    float xv;   // holds chunk c+1 while chunk c is staged in LDS
    {
        const int r = tid >> 7, off = tid & 127;
        xv = x[((size_t)(bbase + r) * Tq + 32 + (off >> 2)) * INq + (off & 3)];
    }
    __syncthreads();

    float hsumA = 0.f, hsumB = 0.f;
    const int rowc = lc & 3;             // replicated A-row

    for (int c = 0; c < 64; ++c) {
        // ---- chunk head: stage chunk c+1 (from xv) into buf[(c+1)&1];
        //      prefetch chunk c+2 into xv (HBM latency spans whole chunk; bar_lds
        //      drains lgkm only, so the vm load is never waited at barriers).
        {
            const int r = tid >> 7, off = tid & 127;
            xstage[(c + 1) & 1][r * 128 + off] = xv;
            int tel = c * 32 + 64 + (off >> 2);
            tel = (tel < Tq) ? tel : (Tq - 1);
            xv = x[((size_t)(bbase + r) * Tq + tel) * INq + (off & 3)];
        }
        const float* __restrict__ xs = xstage[c & 1];

        for (int i = 0; i < 32; ++i) {
            // ---- P0: pre = h @ W_bb[4:] (MFMA, K=256) + x_t . W_bb[0:4] (VALU)
            f32x4 xr = *(const f32x4*)&xs[l4 * 128 + i * 4];   // issue early
            f32x4 p0 = {0.f,0.f,0.f,0.f}, p1 = {0.f,0.f,0.f,0.f};
            f32x4 p2 = {0.f,0.f,0.f,0.f}, p3 = {0.f,0.f,0.f,0.f};
            __builtin_amdgcn_s_setprio(1);
            #pragma unroll
            for (int kt = 0; kt < 8; ++kt) {
                bf16x8 a = *(const bf16x8*)&hb[rowc * HBS + kt * 32 + l4 * 8];
                switch (kt & 3) {
                    case 0: p0 = __builtin_amdgcn_mfma_f32_16x16x32_bf16(a, WB[kt], p0, 0, 0, 0); break;
                    case 1: p1 = __builtin_amdgcn_mfma_f32_16x16x32_bf16(a, WB[kt], p1, 0, 0, 0); break;
                    case 2: p2 = __builtin_amdgcn_mfma_f32_16x16x32_bf16(a, WB[kt], p2, 0, 0, 0); break;
                    case 3: p3 = __builtin_amdgcn_mfma_f32_16x16x32_bf16(a, WB[kt], p3, 0, 0, 0); break;
                }
            }
            __builtin_amdgcn_s_setprio(0);
            {   // x-dot computes while MFMAs drain (independent of them)
                float xd = bias_bb_r + xr[0] * Wx0 + xr[1] * Wx1
                                     + xr[2] * Wx2 + xr[3] * Wx3;
                f32x4 s = (p0 + p1) + (p2 + p3);
                float pre = sel4(s, l4) + xd;        // real row l4, col cb
                bbuf[l4 * BBS + cb] = (__bf16)lecun_f(pre);
            }
            bar_lds();   // bar A

            // ---- P1: heads (K = 128) ----------------------------------------
            f32x4 acc[3][2] = {};
            __builtin_amdgcn_s_setprio(1);
            #pragma unroll
            for (int kt = 0; kt < 4; ++kt) {
                bf16x8 a = *(const bf16x8*)&bbuf[rowc * BBS + kt * 32 + l4 * 8];
                #pragma unroll
                for (int hh = 0; hh < 3; ++hh)
                    #pragma unroll
                    for (int tl = 0; tl < 2; ++tl)
                        acc[hh][tl] = __builtin_amdgcn_mfma_f32_16x16x32_bf16(a, WH[hh][tl][kt], acc[hh][tl], 0, 0, 0);
            }
            __builtin_amdgcn_s_setprio(0);
            {   // lane: row l4, units ru0, ru0+1 (register selects, no LDS)
                float f1a = tanh_f(sel4(acc[0][0], l4) + bf1a);
                float f1b = tanh_f(sel4(acc[0][1], l4) + bf1b);
                float f2a = tanh_f(sel4(acc[1][0], l4) + bf2a);
                float f2b = tanh_f(sel4(acc[1][1], l4) + bf2b);
                float tta = sigm_f(sel4(acc[2][0], l4) + bta_);
                float ttb = sigm_f(sel4(acc[2][1], l4) + btb_);
                float ha  = f1a + tta * (f2a - f1a);
                float hbv = f1b + ttb * (f2b - f1b);
                hsumA += ha; hsumB += hbv;
                union { __bf16 b[2]; unsigned int u; } pk;
                pk.b[0] = (__bf16)ha; pk.b[1] = (__bf16)hbv;
                *(unsigned int*)&hb[l4 * HBS + ru0] = pk.u;
            }
            bar_lds();   // bar B
        }
    }

    // ---------------- epilogue: out = (hsum/T) @ W_fc + b_fc -----------------
    *(f32x2*)&hsum_lds[l4][ru0] = (f32x2){hsumA, hsumB};
    __syncthreads();
    if (w == 0 && l < 40) {
        const int r = l / 10, c = l % 10;
        float s = 0.f;
        #pragma unroll 8
        for (int u = 0; u < 256; ++u)
            s += hsum_lds[r][u] * W_fc[u * NCq + c];
        out[(bbase + r) * NCq + c] = s * (1.0f / Tq) + b_fc[c];
    }
}

extern "C" void kernel_launch(void* const* d_in, const int* in_sizes, int n_in,
                              void* d_out, int out_size, void* d_ws, size_t ws_size,
                              hipStream_t stream) {
    const float* x     = (const float*)d_in[0];
    const float* W_bb  = (const float*)d_in[1];
    const float* b_bb  = (const float*)d_in[2];
    const float* W_ff1 = (const float*)d_in[3];
    const float* b_ff1 = (const float*)d_in[4];
    const float* W_ff2 = (const float*)d_in[5];
    const float* b_ff2 = (const float*)d_in[6];
    const float* W_ta  = (const float*)d_in[7];
    const float* b_ta  = (const float*)d_in[8];
    const float* W_tb  = (const float*)d_in[9];
    const float* b_tb  = (const float*)d_in[10];
    const float* W_fc  = (const float*)d_in[11];
    const float* b_fc  = (const float*)d_in[12];
    float* out = (float*)d_out;

    hipLaunchKernelGGL(cfc_kernel, dim3(256), dim3(512), 0, stream,
                       x, W_bb, b_bb, W_ff1, b_ff1, W_ff2, b_ff2,
                       W_ta, b_ta, W_tb, b_tb, W_fc, b_fc, out);
}

// Round 8
// 1822.276 us; speedup vs baseline: 1.0102x; 1.0102x over previous
//
#include <hip/hip_runtime.h>

#define Tq     2048
#define INq    4
#define UNITSq 256
#define BBq    128
#define NCq    10
#define HBS    288   // hb row stride elems (576B; 576 mod 128B = 64 -> rows alternate 16-bank halves)
#define BBS    160   // bbuf row stride elems (320B; same parity trick)
#define XSS    132   // xstage row stride floats (528B = 33*16B: aligned, banks l4*4 mod 32 distinct)

typedef __bf16 bf16x8 __attribute__((ext_vector_type(8)));
typedef float  f32x4  __attribute__((ext_vector_type(4)));
typedef float  f32x2  __attribute__((ext_vector_type(2)));

__device__ __forceinline__ float rcpf(float x) { return __builtin_amdgcn_rcpf(x); }
__device__ __forceinline__ float tanh_f(float x) {
    float e = __expf(x + x);
    return 1.0f - 2.0f * rcpf(e + 1.0f);
}
__device__ __forceinline__ float lecun_f(float x) {
    float e = __expf(1.332f * x);
    return 1.7159f - 3.4318f * rcpf(e + 1.0f);
}
__device__ __forceinline__ float sigm_f(float x) {
    return rcpf(1.0f + __expf(-x));
}
__device__ __forceinline__ float sel4(f32x4 v, int i) {
    float lo = (i & 1) ? v[1] : v[0];
    float hi = (i & 1) ? v[3] : v[2];
    return (i & 2) ? hi : lo;
}

// LDS-only barrier: drain ds ops, block barrier, fence scheduler both sides
// (rule 18: sched_barrier(0) so MFMA/VALU aren't hoisted across).
__device__ __forceinline__ void bar_lds() {
    __builtin_amdgcn_sched_barrier(0);
    asm volatile("s_waitcnt lgkmcnt(0)" ::: "memory");
    __builtin_amdgcn_s_barrier();
    __builtin_amdgcn_sched_barrier(0);
}

// 256 blocks x 512 threads. Block owns batch rows [4b,4b+4).
// Row replication j&3: A-tile row j = real row (j&3); C/D reg i = real row i
// in every lane -> redistribution is a register select (sel4); lane's row = l4.
// Wave w: P0 cols [16w,16w+16); P1 units u = 32w + 2*lc + {0,1}.
// x (IN=4) handled on VALU: 4 fp32 FMAs per lane, off the MFMA critical path.
__global__ __launch_bounds__(512, 2) void cfc_kernel(
    const float* __restrict__ x,
    const float* __restrict__ W_bb, const float* __restrict__ b_bb,
    const float* __restrict__ W_ff1, const float* __restrict__ b_ff1,
    const float* __restrict__ W_ff2, const float* __restrict__ b_ff2,
    const float* __restrict__ W_ta, const float* __restrict__ b_ta,
    const float* __restrict__ W_tb, const float* __restrict__ b_tb,
    const float* __restrict__ W_fc, const float* __restrict__ b_fc,
    float* __restrict__ out)
{
    const int tid = threadIdx.x;
    const int w   = tid >> 6;
    const int l   = tid & 63;
    const int l4  = l >> 4;
    const int lc  = l & 15;
    const int bbase = blockIdx.x * 4;

    __shared__ __bf16 hb[4 * HBS];                      // cols 0..255 = h
    __shared__ __bf16 bbuf[4 * BBS];                    // cols 0..127 = bb
    __shared__ __align__(16) float xstage[2][4 * XSS];  // [row r][step i*4+q], stride XSS
    __shared__ float  hsum_lds[4][256];

    // ---------------- weight preload (register-resident B-fragments) ---------
    bf16x8 WH[3][2][4];                  // [ff1, ff2, ta+tb][unit tile][ktile]
    #pragma unroll
    for (int tl = 0; tl < 2; ++tl) {
        const int u = w * 32 + 2 * lc + tl;
        #pragma unroll
        for (int kt = 0; kt < 4; ++kt) {
            bf16x8 f1, f2, ts;
            #pragma unroll
            for (int j = 0; j < 8; ++j) {
                const int k = kt * 32 + l4 * 8 + j;
                f1[j] = (__bf16)W_ff1[k * UNITSq + u];
                f2[j] = (__bf16)W_ff2[k * UNITSq + u];
                ts[j] = (__bf16)(W_ta[k * UNITSq + u] + W_tb[k * UNITSq + u]);
            }
            WH[0][tl][kt] = f1; WH[1][tl][kt] = f2; WH[2][tl][kt] = ts;
        }
    }
    const int cb = w * 16 + lc;
    bf16x8 WB[8];                        // h-part only (K = 256 exact)
    #pragma unroll
    for (int kt = 0; kt < 8; ++kt) {
        bf16x8 f;
        #pragma unroll
        for (int j = 0; j < 8; ++j) {
            const int k = kt * 32 + l4 * 8 + j;
            f[j] = (__bf16)W_bb[(4 + k) * BBq + cb];
        }
        WB[kt] = f;
    }
    // x-part of W_bb as fp32 (VALU path)
    const float Wx0 = W_bb[0 * BBq + cb];
    const float Wx1 = W_bb[1 * BBq + cb];
    const float Wx2 = W_bb[2 * BBq + cb];
    const float Wx3 = W_bb[3 * BBq + cb];

    const float bias_bb_r = b_bb[cb];
    const int ru0 = w * 32 + 2 * lc;
    const float bf1a = b_ff1[ru0], bf1b = b_ff1[ru0 + 1];
    const float bf2a = b_ff2[ru0], bf2b = b_ff2[ru0 + 1];
    const float bta_ = b_ta[ru0] + b_tb[ru0];
    const float btb_ = b_ta[ru0 + 1] + b_tb[ru0 + 1];

    // ---------------- init ---------------------------------------------------
    for (int i = tid; i < 4 * HBS; i += 512) hb[i] = (__bf16)0.0f;
    {
        const int r = tid >> 7, off = tid & 127;
        xstage[0][r * XSS + off] = x[((size_t)(bbase + r) * Tq + (off >> 2)) * INq + (off & 3)];
    }
    float xv;   // holds chunk c+1 while chunk c is staged in LDS
    {
        const int r = tid >> 7, off = tid & 127;
        xv = x[((size_t)(bbase + r) * Tq + 32 + (off >> 2)) * INq + (off & 3)];
    }
    __syncthreads();

    float hsumA = 0.f, hsumB = 0.f;
    const int rowc = lc & 3;             // replicated A-row

    for (int c = 0; c < 64; ++c) {
        // ---- chunk head: stage chunk c+1 (from xv) into buf[(c+1)&1];
        //      prefetch chunk c+2 into xv (HBM latency spans whole chunk; bar_lds
        //      drains lgkm only, so the vm load is never waited at barriers).
        {
            const int r = tid >> 7, off = tid & 127;
            xstage[(c + 1) & 1][r * XSS + off] = xv;
            int tel = c * 32 + 64 + (off >> 2);
            tel = (tel < Tq) ? tel : (Tq - 1);
            xv = x[((size_t)(bbase + r) * Tq + tel) * INq + (off & 3)];
        }
        const float* __restrict__ xs = xstage[c & 1];

        for (int i = 0; i < 32; ++i) {
            // ---- P0: pre = h @ W_bb[4:] (MFMA, K=256) + x_t . W_bb[0:4] (VALU)
            f32x4 xr = *(const f32x4*)&xs[l4 * XSS + i * 4];   // conflict-free broadcast
            f32x4 p0 = {0.f,0.f,0.f,0.f}, p1 = {0.f,0.f,0.f,0.f};
            f32x4 p2 = {0.f,0.f,0.f,0.f}, p3 = {0.f,0.f,0.f,0.f};
            __builtin_amdgcn_s_setprio(1);
            #pragma unroll
            for (int kt = 0; kt < 8; ++kt) {
                bf16x8 a = *(const bf16x8*)&hb[rowc * HBS + kt * 32 + l4 * 8];
                switch (kt & 3) {
                    case 0: p0 = __builtin_amdgcn_mfma_f32_16x16x32_bf16(a, WB[kt], p0, 0, 0, 0); break;
                    case 1: p1 = __builtin_amdgcn_mfma_f32_16x16x32_bf16(a, WB[kt], p1, 0, 0, 0); break;
                    case 2: p2 = __builtin_amdgcn_mfma_f32_16x16x32_bf16(a, WB[kt], p2, 0, 0, 0); break;
                    case 3: p3 = __builtin_amdgcn_mfma_f32_16x16x32_bf16(a, WB[kt], p3, 0, 0, 0); break;
                }
            }
            __builtin_amdgcn_s_setprio(0);
            {   // x-dot computes while MFMAs drain (independent of them)
                float xd = bias_bb_r + xr[0] * Wx0 + xr[1] * Wx1
                                     + xr[2] * Wx2 + xr[3] * Wx3;
                f32x4 s = (p0 + p1) + (p2 + p3);
                float pre = sel4(s, l4) + xd;        // real row l4, col cb
                bbuf[l4 * BBS + cb] = (__bf16)lecun_f(pre);
            }
            bar_lds();   // bar A

            // ---- P1: heads (K = 128) ----------------------------------------
            f32x4 acc[3][2] = {};
            __builtin_amdgcn_s_setprio(1);
            #pragma unroll
            for (int kt = 0; kt < 4; ++kt) {
                bf16x8 a = *(const bf16x8*)&bbuf[rowc * BBS + kt * 32 + l4 * 8];
                #pragma unroll
                for (int hh = 0; hh < 3; ++hh)
                    #pragma unroll
                    for (int tl = 0; tl < 2; ++tl)
                        acc[hh][tl] = __builtin_amdgcn_mfma_f32_16x16x32_bf16(a, WH[hh][tl][kt], acc[hh][tl], 0, 0, 0);
            }
            __builtin_amdgcn_s_setprio(0);
            {   // lane: row l4, units ru0, ru0+1 (register selects, no LDS)
                float f1a = tanh_f(sel4(acc[0][0], l4) + bf1a);
                float f1b = tanh_f(sel4(acc[0][1], l4) + bf1b);
                float f2a = tanh_f(sel4(acc[1][0], l4) + bf2a);
                float f2b = tanh_f(sel4(acc[1][1], l4) + bf2b);
                float tta = sigm_f(sel4(acc[2][0], l4) + bta_);
                float ttb = sigm_f(sel4(acc[2][1], l4) + btb_);
                float ha  = f1a + tta * (f2a - f1a);
                float hbv = f1b + ttb * (f2b - f1b);
                hsumA += ha; hsumB += hbv;
                union { __bf16 b[2]; unsigned int u; } pk;
                pk.b[0] = (__bf16)ha; pk.b[1] = (__bf16)hbv;
                *(unsigned int*)&hb[l4 * HBS + ru0] = pk.u;
            }
            bar_lds();   // bar B
        }
    }

    // ---------------- epilogue: out = (hsum/T) @ W_fc + b_fc -----------------
    *(f32x2*)&hsum_lds[l4][ru0] = (f32x2){hsumA, hsumB};
    __syncthreads();
    if (w == 0 && l < 40) {
        const int r = l / 10, c = l % 10;
        float s = 0.f;
        #pragma unroll 8
        for (int u = 0; u < 256; ++u)
            s += hsum_lds[r][u] * W_fc[u * NCq + c];
        out[(bbase + r) * NCq + c] = s * (1.0f / Tq) + b_fc[c];
    }
}

extern "C" void kernel_launch(void* const* d_in, const int* in_sizes, int n_in,
                              void* d_out, int out_size, void* d_ws, size_t ws_size,
                              hipStream_t stream) {
    const float* x     = (const float*)d_in[0];
    const float* W_bb  = (const float*)d_in[1];
    const float* b_bb  = (const float*)d_in[2];
    const float* W_ff1 = (const float*)d_in[3];
    const float* b_ff1 = (const float*)d_in[4];
    const float* W_ff2 = (const float*)d_in[5];
    const float* b_ff2 = (const float*)d_in[6];
    const float* W_ta  = (const float*)d_in[7];
    const float* b_ta  = (const float*)d_in[8];
    const float* W_tb  = (const float*)d_in[9];
    const float* b_tb  = (const float*)d_in[10];
    const float* W_fc  = (const float*)d_in[11];
    const float* b_fc  = (const float*)d_in[12];
    float* out = (float*)d_out;

    hipLaunchKernelGGL(cfc_kernel, dim3(256), dim3(512), 0, stream,
                       x, W_bb, b_bb, W_ff1, b_ff1, W_ff2, b_ff2,
                       W_ta, b_ta, W_tb, b_tb, W_fc, b_fc, out);
}

// Round 9
// 1762.244 us; speedup vs baseline: 1.0446x; 1.0341x over previous
//
#include <hip/hip_runtime.h>

#define Tq     2048
#define INq    4
#define UNITSq 256
#define BBq    128
#define NCq    10
#define HBS    288   // hb row stride elems (576B; rows alternate 16-bank halves; 4-row dup reads -> 2-way = free)
#define BBS    160   // bbuf row stride elems (320B; same parity trick)
#define XSS    132   // xstage row stride floats (528B: 16B-aligned, l4*XSS banks distinct)

typedef __bf16 bf16x8 __attribute__((ext_vector_type(8)));
typedef float  f32x4  __attribute__((ext_vector_type(4)));
typedef float  f32x2  __attribute__((ext_vector_type(2)));

__device__ __forceinline__ float rcpf(float x) { return __builtin_amdgcn_rcpf(x); }
__device__ __forceinline__ float tanh_f(float x) {
    float e = __expf(x + x);
    return 1.0f - 2.0f * rcpf(e + 1.0f);
}
__device__ __forceinline__ float lecun_f(float x) {
    float e = __expf(1.332f * x);
    return 1.7159f - 3.4318f * rcpf(e + 1.0f);
}
__device__ __forceinline__ float sigm_f(float x) {
    return rcpf(1.0f + __expf(-x));
}
__device__ __forceinline__ float sel4(f32x4 v, int i) {
    float lo = (i & 1) ? v[1] : v[0];
    float hi = (i & 1) ? v[3] : v[2];
    return (i & 2) ? hi : lo;
}

// LDS-only barrier: drain ds ops, block barrier, fence scheduler both sides.
__device__ __forceinline__ void bar_lds() {
    __builtin_amdgcn_sched_barrier(0);
    asm volatile("s_waitcnt lgkmcnt(0)" ::: "memory");
    __builtin_amdgcn_s_barrier();
    __builtin_amdgcn_sched_barrier(0);
}

// 256 blocks x 512 threads. Block owns batch rows [4b,4b+4).
// Row replication j&3; C/D reg i = real row i in every lane -> sel4 select.
// Wave w: P0 cols [16w,16w+16); P1 units u = 32w + 2*lc + {0,1}.
// x (IN=4) on VALU fp32, off the MFMA critical path.
__global__ __launch_bounds__(512, 2) void cfc_kernel(
    const float* __restrict__ x,
    const float* __restrict__ W_bb, const float* __restrict__ b_bb,
    const float* __restrict__ W_ff1, const float* __restrict__ b_ff1,
    const float* __restrict__ W_ff2, const float* __restrict__ b_ff2,
    const float* __restrict__ W_ta, const float* __restrict__ b_ta,
    const float* __restrict__ W_tb, const float* __restrict__ b_tb,
    const float* __restrict__ W_fc, const float* __restrict__ b_fc,
    float* __restrict__ out)
{
    const int tid = threadIdx.x;
    const int w   = tid >> 6;
    const int l   = tid & 63;
    const int l4  = l >> 4;
    const int lc  = l & 15;
    const int bbase = blockIdx.x * 4;

    __shared__ __bf16 hb[4 * HBS];                      // cols 0..255 = h
    __shared__ __bf16 bbuf[4 * BBS];                    // cols 0..127 = bb
    __shared__ __align__(16) float xstage[2][4 * XSS];
    __shared__ float  hsum_lds[4][256];

    // ---------------- weight preload (register-resident B-fragments) ---------
    bf16x8 WH[3][2][4];                  // [ff1, ff2, ta+tb][unit tile][ktile]
    #pragma unroll
    for (int tl = 0; tl < 2; ++tl) {
        const int u = w * 32 + 2 * lc + tl;
        #pragma unroll
        for (int kt = 0; kt < 4; ++kt) {
            bf16x8 f1, f2, ts;
            #pragma unroll
            for (int j = 0; j < 8; ++j) {
                const int k = kt * 32 + l4 * 8 + j;
                f1[j] = (__bf16)W_ff1[k * UNITSq + u];
                f2[j] = (__bf16)W_ff2[k * UNITSq + u];
                ts[j] = (__bf16)(W_ta[k * UNITSq + u] + W_tb[k * UNITSq + u]);
            }
            WH[0][tl][kt] = f1; WH[1][tl][kt] = f2; WH[2][tl][kt] = ts;
        }
    }
    const int cb = w * 16 + lc;
    bf16x8 WB[8];                        // h-part only (K = 256 exact)
    #pragma unroll
    for (int kt = 0; kt < 8; ++kt) {
        bf16x8 f;
        #pragma unroll
        for (int j = 0; j < 8; ++j) {
            const int k = kt * 32 + l4 * 8 + j;
            f[j] = (__bf16)W_bb[(4 + k) * BBq + cb];
        }
        WB[kt] = f;
    }
    const float Wx0 = W_bb[0 * BBq + cb];
    const float Wx1 = W_bb[1 * BBq + cb];
    const float Wx2 = W_bb[2 * BBq + cb];
    const float Wx3 = W_bb[3 * BBq + cb];

    const float bias_bb_r = b_bb[cb];
    const int ru0 = w * 32 + 2 * lc;
    const float bf1a = b_ff1[ru0], bf1b = b_ff1[ru0 + 1];
    const float bf2a = b_ff2[ru0], bf2b = b_ff2[ru0 + 1];
    const float bta_ = b_ta[ru0] + b_tb[ru0];
    const float btb_ = b_ta[ru0 + 1] + b_tb[ru0 + 1];

    // ---------------- init ---------------------------------------------------
    for (int i = tid; i < 4 * HBS; i += 512) hb[i] = (__bf16)0.0f;
    {
        const int r = tid >> 7, off = tid & 127;
        xstage[0][r * XSS + off] = x[((size_t)(bbase + r) * Tq + (off >> 2)) * INq + (off & 3)];
    }
    float xv;
    {
        const int r = tid >> 7, off = tid & 127;
        xv = x[((size_t)(bbase + r) * Tq + 32 + (off >> 2)) * INq + (off & 3)];
    }
    __syncthreads();

    float hsumA = 0.f, hsumB = 0.f;
    const int rowc = lc & 3;             // replicated A-row

    for (int c = 0; c < 64; ++c) {
        // stage chunk c+1 from reg; prefetch chunk c+2 (vm latency spans chunk;
        // bar_lds drains lgkm only so the global load is never waited at barriers)
        {
            const int r = tid >> 7, off = tid & 127;
            xstage[(c + 1) & 1][r * XSS + off] = xv;
            int tel = c * 32 + 64 + (off >> 2);
            tel = (tel < Tq) ? tel : (Tq - 1);
            xv = x[((size_t)(bbase + r) * Tq + tel) * INq + (off & 3)];
        }
        const float* __restrict__ xs = xstage[c & 1];

        for (int i = 0; i < 32; ++i) {
            // ---- P0: pre = h @ W_bb[4:] (MFMA K=256) + x . W_bb[0:4] (VALU) --
            // upfront loads: pipeline all 9 lgkm ops before the MFMA chain
            f32x4 xr = *(const f32x4*)&xs[l4 * XSS + i * 4];
            bf16x8 ah[8];
            #pragma unroll
            for (int kt = 0; kt < 8; ++kt)
                ah[kt] = *(const bf16x8*)&hb[rowc * HBS + kt * 32 + l4 * 8];

            f32x4 p0 = {bias_bb_r, bias_bb_r, bias_bb_r, bias_bb_r};
            f32x4 p1 = {0.f,0.f,0.f,0.f};
            f32x4 p2 = {0.f,0.f,0.f,0.f};
            f32x4 p3 = {0.f,0.f,0.f,0.f};
            __builtin_amdgcn_s_setprio(1);
            #pragma unroll
            for (int kt = 0; kt < 8; ++kt) {
                switch (kt & 3) {
                    case 0: p0 = __builtin_amdgcn_mfma_f32_16x16x32_bf16(ah[kt], WB[kt], p0, 0, 0, 0); break;
                    case 1: p1 = __builtin_amdgcn_mfma_f32_16x16x32_bf16(ah[kt], WB[kt], p1, 0, 0, 0); break;
                    case 2: p2 = __builtin_amdgcn_mfma_f32_16x16x32_bf16(ah[kt], WB[kt], p2, 0, 0, 0); break;
                    case 3: p3 = __builtin_amdgcn_mfma_f32_16x16x32_bf16(ah[kt], WB[kt], p3, 0, 0, 0); break;
                }
            }
            __builtin_amdgcn_s_setprio(0);
            {
                float xd = xr[0] * Wx0 + xr[1] * Wx1 + xr[2] * Wx2 + xr[3] * Wx3;
                f32x4 s = (p0 + p1) + (p2 + p3);
                float pre = sel4(s, l4) + xd;        // real row l4, col cb
                bbuf[l4 * BBS + cb] = (__bf16)lecun_f(pre);
            }
            bar_lds();   // bar A

            // ---- P1: heads (K = 128), upfront loads --------------------------
            bf16x8 ab[4];
            #pragma unroll
            for (int kt = 0; kt < 4; ++kt)
                ab[kt] = *(const bf16x8*)&bbuf[rowc * BBS + kt * 32 + l4 * 8];

            f32x4 acc[3][2];
            acc[0][0] = (f32x4){bf1a, bf1a, bf1a, bf1a};
            acc[0][1] = (f32x4){bf1b, bf1b, bf1b, bf1b};
            acc[1][0] = (f32x4){bf2a, bf2a, bf2a, bf2a};
            acc[1][1] = (f32x4){bf2b, bf2b, bf2b, bf2b};
            acc[2][0] = (f32x4){bta_, bta_, bta_, bta_};
            acc[2][1] = (f32x4){btb_, btb_, btb_, btb_};
            __builtin_amdgcn_s_setprio(1);
            #pragma unroll
            for (int kt = 0; kt < 4; ++kt)
                #pragma unroll
                for (int hh = 0; hh < 3; ++hh)
                    #pragma unroll
                    for (int tl = 0; tl < 2; ++tl)
                        acc[hh][tl] = __builtin_amdgcn_mfma_f32_16x16x32_bf16(ab[kt], WH[hh][tl][kt], acc[hh][tl], 0, 0, 0);
            __builtin_amdgcn_s_setprio(0);
            {   // lane: row l4, units ru0, ru0+1 — write first (gates barrier),
                // hsum accumulate after
                float f1a = tanh_f(sel4(acc[0][0], l4));
                float f1b = tanh_f(sel4(acc[0][1], l4));
                float f2a = tanh_f(sel4(acc[1][0], l4));
                float f2b = tanh_f(sel4(acc[1][1], l4));
                float tta = sigm_f(sel4(acc[2][0], l4));
                float ttb = sigm_f(sel4(acc[2][1], l4));
                float ha  = f1a + tta * (f2a - f1a);
                float hbv = f1b + ttb * (f2b - f1b);
                union { __bf16 b[2]; unsigned int u; } pk;
                pk.b[0] = (__bf16)ha; pk.b[1] = (__bf16)hbv;
                *(unsigned int*)&hb[l4 * HBS + ru0] = pk.u;
                hsumA += ha; hsumB += hbv;
            }
            bar_lds();   // bar B
        }
    }

    // ---------------- epilogue: out = (hsum/T) @ W_fc + b_fc -----------------
    *(f32x2*)&hsum_lds[l4][ru0] = (f32x2){hsumA, hsumB};
    __syncthreads();
    if (w == 0 && l < 40) {
        const int r = l / 10, c = l % 10;
        float s = 0.f;
        #pragma unroll 8
        for (int u = 0; u < 256; ++u)
            s += hsum_lds[r][u] * W_fc[u * NCq + c];
        out[(bbase + r) * NCq + c] = s * (1.0f / Tq) + b_fc[c];
    }
}

extern "C" void kernel_launch(void* const* d_in, const int* in_sizes, int n_in,
                              void* d_out, int out_size, void* d_ws, size_t ws_size,
                              hipStream_t stream) {
    const float* x     = (const float*)d_in[0];
    const float* W_bb  = (const float*)d_in[1];
    const float* b_bb  = (const float*)d_in[2];
    const float* W_ff1 = (const float*)d_in[3];
    const float* b_ff1 = (const float*)d_in[4];
    const float* W_ff2 = (const float*)d_in[5];
    const float* b_ff2 = (const float*)d_in[6];
    const float* W_ta  = (const float*)d_in[7];
    const float* b_ta  = (const float*)d_in[8];
    const float* W_tb  = (const float*)d_in[9];
    const float* b_tb  = (const float*)d_in[10];
    const float* W_fc  = (const float*)d_in[11];
    const float* b_fc  = (const float*)d_in[12];
    float* out = (float*)d_out;

    hipLaunchKernelGGL(cfc_kernel, dim3(256), dim3(512), 0, stream,
                       x, W_bb, b_bb, W_ff1, b_ff1, W_ff2, b_ff2,
                       W_ta, b_ta, W_tb, b_tb, W_fc, b_fc, out);
}